// Round 22
// baseline (169.807 us; speedup 1.0000x reference)
//
#include <hip/hip_runtime.h>
#include <stdint.h>

// ---------------- problem constants ----------------
#define BHN 16          // b*h flat batch
#define TLEN 4096
#define EDIM 64
#define NHASH 8
#define NBUCK 64
#define GBUCK 512
#define NCHUNK 512
#define NITEMS 32768

// ---------------- workspace layout (bytes) ----------------
#define WS_BUCKETS 0u                 // 16*8*4096 u8          = 524288
#define WS_SORTED  557056u            // 16*32768 int          = 2097152
#define WS_LSE     2654208u           // 16*4096*8 f32         = 2097152
#define WS_O       4751360u           // 16*4096*8*64 fp16     = 67108864
#define WS_QK16    71860224u          // 16*4096*64 fp16       = 8388608
#define WS_V16     80248832u          // 16*4096*64 fp16       = 8388608
#define WS_NQ      88637440u          // 16*4096 f32           = 262144
#define WS_RTH     114065408u         // 256*64 fp16           = 32768
#define WS_RTM     114098176u         // 256*64 fp16           = 32768
#define WS_RTL     114130944u         // 256*64 fp16           = 32768
// end ~114.2 MB

typedef __attribute__((ext_vector_type(4))) float f32x4;
typedef __attribute__((ext_vector_type(8))) _Float16 f16x8;     // MFMA A/B frag
typedef __attribute__((ext_vector_type(4))) _Float16 f16x4;
typedef __attribute__((ext_vector_type(4))) unsigned u32x4;

#define LOG2E 1.44269504088896f
#define LN2   0.69314718055995f
#define S11   4.8828125e-4f            // 2^-11
#define S22   2.384185791015625e-7f    // 2^-22

// exact fp16 triple split: x = h + m*2^-11 + l*2^-22 (+ ~2^-33 residual).
static __device__ __forceinline__ void split3(float x, _Float16& h0, _Float16& m0, _Float16& l0) {
  h0 = (_Float16)x;
  float r1 = x - (float)h0;                 // exact (Sterbenz)
  m0 = (_Float16)(r1 * 2048.0f);            // scaled 2^11, exact pow2 scale
  float r2 = r1 - (float)m0 * (1.0f / 2048.0f);  // exact
  l0 = (_Float16)(r2 * 4194304.0f);         // scaled 2^22
}

// ============================================================
// K0: rot transpose + triple-split, parallel over f.
// ============================================================
__global__ __launch_bounds__(256) void k_rotsplit(const float* __restrict__ rot,
                                                  _Float16* __restrict__ rth,
                                                  _Float16* __restrict__ rtm,
                                                  _Float16* __restrict__ rtl) {
  int f = blockIdx.x;
  int n = threadIdx.x;
  float x = rot[f * 256 + n];
  _Float16 h0, m0, l0;
  split3(x, h0, m0, l0);
  rth[n * 64 + f] = h0;
  rtm[n * 64 + f] = m0;
  rtl[n * 64 + f] = l0;
}

// ============================================================
// K1: LSH hash via MFMA, fused prep, 32-token tiles (r21).
// r22: __launch_bounds__(256,6) — force VGPR <= 85 so 6 blocks
// /CU are resident (r21 measured VGPR=100 -> 5, the new cap).
// B-fragments reloaded per kh (L1/L2-hot) to shrink live range.
// Per-element arithmetic unchanged -> buckets bit-identical.
// ============================================================
__global__ __launch_bounds__(256, 6) void k_hash2(const float* __restrict__ qk,
                                                  const float* __restrict__ vin,
                                                  const _Float16* __restrict__ rth,
                                                  const _Float16* __restrict__ rtm,
                                                  const _Float16* __restrict__ rtl,
                                                  uint8_t* __restrict__ buckets,
                                                  _Float16* __restrict__ qk16n,
                                                  _Float16* __restrict__ v16,
                                                  float* __restrict__ nq) {
  __shared__ __attribute__((aligned(16))) _Float16 ah[32 * 64];
  __shared__ __attribute__((aligned(16))) _Float16 am[32 * 64];
  __shared__ __attribute__((aligned(16))) _Float16 al[32 * 64];
  __shared__ float rsum[256];

  int tid = threadIdx.x;
  int bh = blockIdx.x >> 7;            // 16
  int tt = blockIdx.x & 127;           // 128 tiles of 32 tokens
  int b = bh >> 3, head = bh & 7;

  int r = tid & 31, fq8 = tid >> 5;    // 8 groups x 8 floats
  size_t inbase = ((size_t)((b * 4096 + tt * 32 + r) * 8 + head)) * 64 + fq8 * 8;
  size_t obase  = ((size_t)(bh * 4096 + tt * 32 + r)) * 64 + fq8 * 8;

  // ---- stage A: raw qk -> x[8] + norm partial + split3 -> LDS ----
  float x[8];
  {
    const float4* srcq = (const float4*)(qk + inbase);
    float ss = 0.f;
#pragma unroll
    for (int i = 0; i < 2; ++i) {
      float4 v = srcq[i];
      x[4 * i + 0] = v.x; x[4 * i + 1] = v.y;
      x[4 * i + 2] = v.z; x[4 * i + 3] = v.w;
      ss = fmaf(v.x, v.x, ss); ss = fmaf(v.y, v.y, ss);
      ss = fmaf(v.z, v.z, ss); ss = fmaf(v.w, v.w, ss);
    }
    rsum[fq8 * 32 + r] = ss;
  }
  // v stream: load, convert, store
  {
    const float4* srcv = (const float4*)(vin + inbase);
    float4 a = srcv[0], bb2 = srcv[1];
    f16x8 vh;
    vh[0] = (_Float16)a.x;  vh[1] = (_Float16)a.y;
    vh[2] = (_Float16)a.z;  vh[3] = (_Float16)a.w;
    vh[4] = (_Float16)bb2.x; vh[5] = (_Float16)bb2.y;
    vh[6] = (_Float16)bb2.z; vh[7] = (_Float16)bb2.w;
    *(f16x8*)(v16 + obase) = vh;
  }
  // split3 -> LDS (identical per-element arithmetic -> bit-identical buckets)
  {
    int rx = r & 7;
    f16x8 hv, mv, lv;
#pragma unroll
    for (int e = 0; e < 8; ++e) {
      _Float16 h0, m0, l0;
      split3(x[e], h0, m0, l0);
      hv[e] = h0; mv[e] = m0; lv[e] = l0;
    }
    int off = r * 64 + ((fq8 ^ rx) << 3);
    *(f16x8*)&ah[off] = hv;
    *(f16x8*)&am[off] = mv;
    *(f16x8*)&al[off] = lv;
  }
  __syncthreads();

  // ---- norm + qk16n + nq emission ----
  {
    float tot = 0.f;
#pragma unroll
    for (int g = 0; g < 8; ++g) tot += rsum[g * 32 + r];
    float nrm = fmaxf(sqrtf(tot), 1e-12f);
    float inv = 1.f / nrm;
    f16x8 qh;
#pragma unroll
    for (int e = 0; e < 8; ++e) qh[e] = (_Float16)(x[e] * inv);
    *(f16x8*)(qk16n + obase) = qh;
    if (fq8 == 0) nq[(size_t)bh * 4096 + tt * 32 + r] = nrm * LOG2E;
  }

  int w = tid >> 6, l = tid & 63;
  int col = l & 15, kg = l >> 4;

  float bv[2][4];
  int   bi[2][4];

#pragma unroll
  for (int nt = 0; nt < 4; ++nt) {
    int nrow = w * 64 + nt * 16 + col;
    const _Float16* bh_p = rth + nrow * 64 + kg * 8;
    const _Float16* bm_p = rtm + nrow * 64 + kg * 8;
    const _Float16* bl_p = rtl + nrow * 64 + kg * 8;

    f32x4 C0[2], C1[2], C2[2];
#pragma unroll
    for (int mt = 0; mt < 2; ++mt) {
      C0[mt] = (f32x4){0.f, 0.f, 0.f, 0.f};
      C1[mt] = (f32x4){0.f, 0.f, 0.f, 0.f};
      C2[mt] = (f32x4){0.f, 0.f, 0.f, 0.f};
    }

    __builtin_amdgcn_s_setprio(1);
#pragma unroll
    for (int kh = 0; kh < 2; ++kh) {
      // B-frags loaded per kh (3 live, not 6) — L1/L2-hot
      f16x8 Bh = *(const f16x8*)(bh_p + kh * 32);
      f16x8 Bm = *(const f16x8*)(bm_p + kh * 32);
      f16x8 Bl = *(const f16x8*)(bl_p + kh * 32);
      int slot = kh * 4 + kg;
#pragma unroll
      for (int mt = 0; mt < 2; ++mt) {
        int ar = mt * 16 + col, arx = ar & 7;
        f16x8 Ah = *(f16x8*)&ah[ar * 64 + ((slot ^ arx) << 3)];
        f16x8 Am = *(f16x8*)&am[ar * 64 + ((slot ^ arx) << 3)];
        f16x8 Al = *(f16x8*)&al[ar * 64 + ((slot ^ arx) << 3)];
        C2[mt] = __builtin_amdgcn_mfma_f32_16x16x32_f16(Ah, Bl, C2[mt], 0, 0, 0);
        C2[mt] = __builtin_amdgcn_mfma_f32_16x16x32_f16(Al, Bh, C2[mt], 0, 0, 0);
        C2[mt] = __builtin_amdgcn_mfma_f32_16x16x32_f16(Am, Bm, C2[mt], 0, 0, 0);
        C1[mt] = __builtin_amdgcn_mfma_f32_16x16x32_f16(Ah, Bm, C1[mt], 0, 0, 0);
        C1[mt] = __builtin_amdgcn_mfma_f32_16x16x32_f16(Am, Bh, C1[mt], 0, 0, 0);
        C0[mt] = __builtin_amdgcn_mfma_f32_16x16x32_f16(Ah, Bh, C0[mt], 0, 0, 0);
      }
    }
    __builtin_amdgcn_s_setprio(0);

    int ib = (nt & 1) * 16 + col;
#pragma unroll
    for (int mt = 0; mt < 2; ++mt) {
#pragma unroll
      for (int r2 = 0; r2 < 4; ++r2) {
        float V = C0[mt][r2] + C1[mt][r2] * S11 + C2[mt][r2] * S22;
        float av = fabsf(V);
        int fi = (V >= 0.f) ? ib : ib + 32;   // V==0 -> +side (lower idx)
        if ((nt & 1) == 0) {
          bv[mt][r2] = av; bi[mt][r2] = fi;
        } else {
          if (av > bv[mt][r2] || (av == bv[mt][r2] && fi < bi[mt][r2])) {
            bv[mt][r2] = av; bi[mt][r2] = fi;
          }
        }
      }
    }

    if (nt & 1) {
      int h = w * 2 + (nt >> 1);
#pragma unroll
      for (int mt = 0; mt < 2; ++mt) {
#pragma unroll
        for (int r2 = 0; r2 < 4; ++r2) {
          float v = bv[mt][r2]; int i_ = bi[mt][r2];
#pragma unroll
          for (int d = 1; d < 16; d <<= 1) {
            float ov = __shfl_xor(v, d);
            int   oi = __shfl_xor(i_, d);
            if (ov > v || (ov == v && oi < i_)) { v = ov; i_ = oi; }
          }
          if (col == 0) {
            int t = tt * 32 + mt * 16 + kg * 4 + r2;
            buckets[(bh * 8 + h) * 4096 + t] = (uint8_t)i_;
          }
        }
      }
    }
  }
}

// ============================================================
// K2: FUSED hist+scan+rank (r17-verified).
// ============================================================
__global__ __launch_bounds__(64) void k_sort(const uint8_t* __restrict__ buckets,
                                             int* __restrict__ sorted) {
  __shared__ uint8_t bkt[4096];
  __shared__ uint8_t lrk[4096];
  __shared__ int hist[64 * 65];
  __shared__ int sbase[64];
  int tid = threadIdx.x;
  int bh = blockIdx.x >> 3, h = blockIdx.x & 7;

  const int* src = (const int*)(buckets + (size_t)(bh * 8 + h) * 4096);
  for (int k = tid; k < 1024; k += 64) ((int*)bkt)[k] = src[k];
  for (int k = tid; k < 64 * 65; k += 64) hist[k] = 0;
  __syncthreads();

  {
    int c = tid;
    for (int k = 0; k < 64; ++k) {
      int t = c * 64 + k;
      int bin = bkt[t];
      int r = hist[c * 65 + bin];
      hist[c * 65 + bin] = r + 1;
      lrk[t] = (uint8_t)r;
    }
  }
  __syncthreads();

  int run = 0;
  {
    int bb = tid;
    for (int c2 = 0; c2 < 64; ++c2) {
      int val = hist[c2 * 65 + bb];
      hist[c2 * 65 + bb] = run;
      run += val;
    }
  }
  {
    int ex = run;
#pragma unroll
    for (int d = 1; d < 64; d <<= 1) {
      int o = __shfl_up(ex, d);
      if (tid >= d) ex += o;
    }
    ex -= run;                    // exclusive
    sbase[tid] = h * 4096 + ex;   // segment base + local base
  }
  __syncthreads();

  {
    int c = tid;
    int* dst = sorted + (size_t)bh * 32768;
    for (int k = 0; k < 64; ++k) {
      int t = c * 64 + k;
      int bin = bkt[t];
      int pos = sbase[bin] + hist[c * 65 + bin] + (int)lrk[t];
      dst[pos] = h * 4096 + t;
    }
  }
}

// ============================================================
// K3: chunked attention, fp16 MFMA — r15 structure, XCD-local
// grid, hash-innermost o/lse layout (unchanged).
// ============================================================
__global__ __launch_bounds__(256, 4) void k_attn(const _Float16* __restrict__ qk16n,
                                                 const _Float16* __restrict__ v16,
                                                 const float* __restrict__ nq,
                                                 const int* __restrict__ sorted,
                                                 _Float16* __restrict__ o_buf,
                                                 float* __restrict__ lse_buf) {
  __shared__ __attribute__((aligned(16))) _Float16 kf[128 * 64];
  __shared__ __attribute__((aligned(16))) _Float16 vt[64 * 128];
  __shared__ __attribute__((aligned(16))) float pinv_s[64];
  __shared__ __attribute__((aligned(16))) int tv[128];
  __shared__ __attribute__((aligned(16))) int items[64];

  int tid = threadIdx.x;
  int bh = blockIdx.x & 15;      // XCD-local decode
  int c  = blockIdx.x >> 4;

  if (tid < 128) {
    int r = tid;
    int pos = (r < 64) ? (c * 64 + r) : (((c + 511) & 511) * 64 + (r - 64));
    int item = sorted[(size_t)bh * 32768 + pos];
    tv[r] = item & 4095;
    if (r < 64) items[r] = item;
  }
  __syncthreads();

  int w = tid >> 6;
  int l = tid & 63;
  int col = l & 15;
  int kg = l >> 4;
  int rq = w * 16 + col;
  int rqx7 = rq & 7, rqx15 = rq & 15;
  int tq = tv[rq];
  float nqv = nq[(size_t)bh * 4096 + tq];

  {
    int r = tid >> 1, half = tid & 1;
    int t = tv[r];
    const f16x8* src = (const f16x8*)(qk16n + ((size_t)(bh * 4096 + t)) * 64 + half * 32);
    f16x8 d0 = src[0], d1 = src[1], d2 = src[2], d3 = src[3];
    int rx = r & 7, s0 = half * 4;
    *(f16x8*)&kf[r * 64 + (((s0 + 0) ^ rx) << 3)] = d0;
    *(f16x8*)&kf[r * 64 + (((s0 + 1) ^ rx) << 3)] = d1;
    *(f16x8*)&kf[r * 64 + (((s0 + 2) ^ rx) << 3)] = d2;
    *(f16x8*)&kf[r * 64 + (((s0 + 3) ^ rx) << 3)] = d3;
  }

  {
    int jp = tid & 63, db = tid >> 6, f0 = db * 16;
    int t0 = tv[2 * jp], t1 = tv[2 * jp + 1];
    const u32x4* s0p = (const u32x4*)(v16 + ((size_t)(bh * 4096 + t0)) * 64 + f0);
    const u32x4* s1p = (const u32x4*)(v16 + ((size_t)(bh * 4096 + t1)) * 64 + f0);
    u32x4 lo0 = s0p[0], hi0 = s0p[1];
    u32x4 lo1 = s1p[0], hi1 = s1p[1];
    int jbase = ((jp >> 2));
    int joff = (jp & 3) << 1;
#pragma unroll
    for (int i = 0; i < 16; ++i) {
      int d = f0 + i;
      unsigned a = (i < 8) ? lo0[(i >> 1) & 3] : hi0[(i >> 1) & 3];
      unsigned bsrc = (i < 8) ? lo1[(i >> 1) & 3] : hi1[(i >> 1) & 3];
      unsigned sel = (i & 1) ? 0x07060302u : 0x05040100u;
      unsigned pack = __builtin_amdgcn_perm(bsrc, a, sel);
      *(unsigned*)&vt[d * 128 + ((jbase ^ (d & 15)) << 3) + joff] = pack;
    }
  }
  __syncthreads();

  f16x8 qf[2];
#pragma unroll
  for (int ks = 0; ks < 2; ++ks)
    qf[ks] = *(f16x8*)&kf[rq * 64 + (((ks * 4 + kg) ^ rqx7) << 3)];

  f32x4 S[8];
#pragma unroll
  for (int mt = 0; mt < 8; ++mt) S[mt] = (f32x4){0.f, 0.f, 0.f, 0.f};

  __builtin_amdgcn_s_setprio(1);
#pragma unroll
  for (int mt = 0; mt < 8; ++mt) {
    int rj = mt * 16 + col;
    int rjx = rj & 7;
#pragma unroll
    for (int ks = 0; ks < 2; ++ks) {
      f16x8 a = *(f16x8*)&kf[rj * 64 + (((ks * 4 + kg) ^ rjx) << 3)];
      S[mt] = __builtin_amdgcn_mfma_f32_16x16x32_f16(a, qf[ks], S[mt], 0, 0, 0);
    }
  }
  __builtin_amdgcn_s_setprio(0);

  float vals[32];
  float mx = -1e30f;
#pragma unroll
  for (int mt = 0; mt < 8; ++mt) {
    int j0 = mt * 16 + kg * 4;
    int4 tk4 = *(int4*)&tv[j0];
    int tki[4] = {tk4.x, tk4.y, tk4.z, tk4.w};
#pragma unroll
    for (int r = 0; r < 4; ++r) {
      float d = S[mt][r] * nqv;
      if (tki[r] == tq) d = -50000.0f * LOG2E;
      vals[mt * 4 + r] = d;
      mx = fmaxf(mx, d);
    }
  }
  mx = fmaxf(mx, __shfl_xor(mx, 16));
  mx = fmaxf(mx, __shfl_xor(mx, 32));
  float ssum = 0.f;
#pragma unroll
  for (int i = 0; i < 32; ++i) {
    float e = __builtin_amdgcn_exp2f(vals[i] - mx);
    vals[i] = e;
    ssum += e;
  }
  ssum += __shfl_xor(ssum, 16);
  ssum += __shfl_xor(ssum, 32);
  if (kg == 0) {
    int item = items[rq];
    lse_buf[((size_t)bh * 4096 + (item & 4095)) * 8 + (item >> 12)] =
        (mx + __builtin_amdgcn_logf(ssum)) * LN2;
    pinv_s[rq] = 1.f / ssum;
  }

  __syncthreads();

  _Float16* Pb = kf;
#pragma unroll
  for (int mt = 0; mt < 8; ++mt) {
    int j0 = mt * 16 + kg * 4;
    int slot = j0 >> 3;
    int off = rq * 128 + ((slot ^ rqx15) << 3) + ((kg & 1) << 2);
    f16x4 pk;
#pragma unroll
    for (int r = 0; r < 4; ++r) pk[r] = (_Float16)vals[mt * 4 + r];
    *(f16x4*)&Pb[off] = pk;
  }
  asm volatile("s_waitcnt lgkmcnt(0)" ::: "memory");

  f32x4 O[4];
#pragma unroll
  for (int nt = 0; nt < 4; ++nt) O[nt] = (f32x4){0.f, 0.f, 0.f, 0.f};
  __builtin_amdgcn_s_setprio(1);
#pragma unroll
  for (int ks = 0; ks < 4; ++ks) {
    int slot = (ks << 2) + kg;
    f16x8 pa = *(f16x8*)&Pb[rq * 128 + ((slot ^ rqx15) << 3)];
#pragma unroll
    for (int nt = 0; nt < 4; ++nt) {
      int dD = nt * 16 + col;
      f16x8 vb = *(f16x8*)&vt[dD * 128 + ((slot ^ (dD & 15)) << 3)];
      O[nt] = __builtin_amdgcn_mfma_f32_16x16x32_f16(pa, vb, O[nt], 0, 0, 0);
    }
  }
  __builtin_amdgcn_s_setprio(0);

  {
    int i0 = w * 16 + kg * 4;
    int4 it4 = *(int4*)&items[i0];
    float4 pv4 = *(float4*)&pinv_s[i0];
    int iti[4] = {it4.x, it4.y, it4.z, it4.w};
    float pvi[4] = {pv4.x, pv4.y, pv4.z, pv4.w};
#pragma unroll
    for (int r = 0; r < 4; ++r) {
      int item = iti[r];
      _Float16* orow = o_buf +
          (((size_t)bh * 4096 + (item & 4095)) * 8 + (item >> 12)) * 64;
#pragma unroll
      for (int nt = 0; nt < 4; ++nt) orow[nt * 16 + col] = (_Float16)(O[nt][r] * pvi[r]);
    }
  }
}

// ============================================================
// K4: combine 8 hash rounds — hash-innermost layout (r18).
// ============================================================
__global__ __launch_bounds__(256) void k_combine(const _Float16* __restrict__ o_buf,
                                                 const float* __restrict__ lse_buf,
                                                 float* __restrict__ out) {
  int gid = blockIdx.x * 256 + threadIdx.x;  // < 16*4096*16
  int d4 = gid & 15;
  int t  = (gid >> 4) & 4095;
  int bh = gid >> 16;

  const float* lrow = lse_buf + ((size_t)bh * 4096 + t) * 8;
  float lx[8];
#pragma unroll
  for (int h = 0; h < 8; ++h) lx[h] = lrow[h];
  float m = lx[0];
#pragma unroll
  for (int h = 1; h < 8; ++h) m = fmaxf(m, lx[h]);
  float wv[8]; float s = 0.f;
#pragma unroll
  for (int h = 0; h < 8; ++h) { wv[h] = __expf(lx[h] - m); s += wv[h]; }
  float inv = 1.f / s;

  const _Float16* obase = o_buf + ((size_t)bh * 4096 + t) * 8 * 64 + d4 * 4;
  float ax = 0.f, ay = 0.f, az = 0.f, aw = 0.f;
#pragma unroll
  for (int h = 0; h < 8; ++h) {
    f16x4 ov = *(const f16x4*)(obase + h * 64);
    ax = fmaf(wv[h], (float)ov[0], ax);
    ay = fmaf(wv[h], (float)ov[1], ay);
    az = fmaf(wv[h], (float)ov[2], az);
    aw = fmaf(wv[h], (float)ov[3], aw);
  }
  *(float4*)(out + ((size_t)(bh * 4096 + t)) * 64 + d4 * 4) =
      make_float4(ax * inv, ay * inv, az * inv, aw * inv);
}

// ============================================================
extern "C" void kernel_launch(void* const* d_in, const int* in_sizes, int n_in,
                              void* d_out, int out_size, void* d_ws, size_t ws_size,
                              hipStream_t stream) {
  const float* qk  = (const float*)d_in[0];
  // d_in[1] ("k") is unused by the reference
  const float* vin = (const float*)d_in[2];
  const float* rot = (const float*)d_in[3];

  uint8_t* ws = (uint8_t*)d_ws;
  uint8_t*  buckets = ws + WS_BUCKETS;
  int*      sorted  = (int*)(ws + WS_SORTED);
  float*    lse_buf = (float*)(ws + WS_LSE);
  _Float16* o_buf   = (_Float16*)(ws + WS_O);
  _Float16* qk16n   = (_Float16*)(ws + WS_QK16);
  _Float16* v16     = (_Float16*)(ws + WS_V16);
  float*    nqbuf   = (float*)(ws + WS_NQ);
  _Float16* rth     = (_Float16*)(ws + WS_RTH);
  _Float16* rtm     = (_Float16*)(ws + WS_RTM);
  _Float16* rtl     = (_Float16*)(ws + WS_RTL);
  float*    out     = (float*)d_out;

  k_rotsplit<<<64, 256, 0, stream>>>(rot, rth, rtm, rtl);
  k_hash2<<<BHN * 128, 256, 0, stream>>>(qk, vin, rth, rtm, rtl, buckets,
                                         qk16n, v16, nqbuf);
  k_sort<<<BHN * NHASH, 64, 0, stream>>>(buckets, sorted);
  k_attn<<<BHN * NCHUNK, 256, 0, stream>>>(qk16n, v16, nqbuf, sorted, o_buf, lse_buf);
  k_combine<<<4096, 256, 0, stream>>>(o_buf, lse_buf, out);
}

// Round 23
// 120.838 us; speedup vs baseline: 1.4052x; 1.4052x over previous
//
#include <hip/hip_runtime.h>
#include <stdint.h>

// ---------------- problem constants ----------------
#define BHN 16          // b*h flat batch
#define TLEN 4096
#define EDIM 64
#define NHASH 8
#define NBUCK 64
#define GBUCK 512
#define NCHUNK 512
#define NITEMS 32768

// ---------------- workspace layout (bytes) ----------------
#define WS_BUCKETS 0u                 // 16*8*4096 u8          = 524288
#define WS_SORTED  557056u            // 16*32768 int          = 2097152
#define WS_LSE     2654208u           // 16*4096*8 f32         = 2097152
#define WS_O       4751360u           // 16*4096*8*64 fp16     = 67108864
#define WS_QK16    71860224u          // 16*4096*64 fp16       = 8388608
#define WS_V16     80248832u          // 16*4096*64 fp16       = 8388608
#define WS_NQ      88637440u          // 16*4096 f32           = 262144
#define WS_RTH     114065408u         // 256*64 fp16           = 32768
#define WS_RTM     114098176u         // 256*64 fp16           = 32768
#define WS_RTL     114130944u         // 256*64 fp16           = 32768
// end ~114.2 MB

typedef __attribute__((ext_vector_type(4))) float f32x4;
typedef __attribute__((ext_vector_type(8))) _Float16 f16x8;     // MFMA A/B frag
typedef __attribute__((ext_vector_type(4))) _Float16 f16x4;
typedef __attribute__((ext_vector_type(4))) unsigned u32x4;

#define LOG2E 1.44269504088896f
#define LN2   0.69314718055995f
#define S11   4.8828125e-4f            // 2^-11
#define S22   2.384185791015625e-7f    // 2^-22

// exact fp16 triple split: x = h + m*2^-11 + l*2^-22 (+ ~2^-33 residual).
static __device__ __forceinline__ void split3(float x, _Float16& h0, _Float16& m0, _Float16& l0) {
  h0 = (_Float16)x;
  float r1 = x - (float)h0;                 // exact (Sterbenz)
  m0 = (_Float16)(r1 * 2048.0f);            // scaled 2^11, exact pow2 scale
  float r2 = r1 - (float)m0 * (1.0f / 2048.0f);  // exact
  l0 = (_Float16)(r2 * 4194304.0f);         // scaled 2^22
}

// ============================================================
// K0: rot transpose + triple-split, parallel over f.
// ============================================================
__global__ __launch_bounds__(256) void k_rotsplit(const float* __restrict__ rot,
                                                  _Float16* __restrict__ rth,
                                                  _Float16* __restrict__ rtm,
                                                  _Float16* __restrict__ rtl) {
  int f = blockIdx.x;
  int n = threadIdx.x;
  float x = rot[f * 256 + n];
  _Float16 h0, m0, l0;
  split3(x, h0, m0, l0);
  rth[n * 64 + f] = h0;
  rtm[n * 64 + f] = m0;
  rtl[n * 64 + f] = l0;
}

// ============================================================
// K1: LSH hash via MFMA, fused prep, 32-token tiles — EXACT
// r21 form (measured: total 121.0 µs, VGPR=100, no scratch).
// r22's __launch_bounds__(256,6) forced VGPR=40 -> massive
// scratch spill (WRITE 17->169MB, 170µs total) -> REVERTED.
// Lesson: 5 waves/SIMD at VGPR=100 is the genuine register
// demand; forcing below demand trades TLP for 10x scratch.
// ============================================================
__global__ __launch_bounds__(256) void k_hash2(const float* __restrict__ qk,
                                               const float* __restrict__ vin,
                                               const _Float16* __restrict__ rth,
                                               const _Float16* __restrict__ rtm,
                                               const _Float16* __restrict__ rtl,
                                               uint8_t* __restrict__ buckets,
                                               _Float16* __restrict__ qk16n,
                                               _Float16* __restrict__ v16,
                                               float* __restrict__ nq) {
  __shared__ __attribute__((aligned(16))) _Float16 ah[32 * 64];
  __shared__ __attribute__((aligned(16))) _Float16 am[32 * 64];
  __shared__ __attribute__((aligned(16))) _Float16 al[32 * 64];
  __shared__ float rsum[256];

  int tid = threadIdx.x;
  int bh = blockIdx.x >> 7;            // 16
  int tt = blockIdx.x & 127;           // 128 tiles of 32 tokens
  int b = bh >> 3, head = bh & 7;

  int r = tid & 31, fq8 = tid >> 5;    // 8 groups x 8 floats
  size_t inbase = ((size_t)((b * 4096 + tt * 32 + r) * 8 + head)) * 64 + fq8 * 8;
  size_t obase  = ((size_t)(bh * 4096 + tt * 32 + r)) * 64 + fq8 * 8;

  // ---- stage A: raw qk -> x[8] + norm partial + split3 -> LDS ----
  float x[8];
  {
    const float4* srcq = (const float4*)(qk + inbase);
    float ss = 0.f;
#pragma unroll
    for (int i = 0; i < 2; ++i) {
      float4 v = srcq[i];
      x[4 * i + 0] = v.x; x[4 * i + 1] = v.y;
      x[4 * i + 2] = v.z; x[4 * i + 3] = v.w;
      ss = fmaf(v.x, v.x, ss); ss = fmaf(v.y, v.y, ss);
      ss = fmaf(v.z, v.z, ss); ss = fmaf(v.w, v.w, ss);
    }
    rsum[fq8 * 32 + r] = ss;
  }
  // v stream: load, convert, store
  {
    const float4* srcv = (const float4*)(vin + inbase);
    float4 a = srcv[0], bb2 = srcv[1];
    f16x8 vh;
    vh[0] = (_Float16)a.x;  vh[1] = (_Float16)a.y;
    vh[2] = (_Float16)a.z;  vh[3] = (_Float16)a.w;
    vh[4] = (_Float16)bb2.x; vh[5] = (_Float16)bb2.y;
    vh[6] = (_Float16)bb2.z; vh[7] = (_Float16)bb2.w;
    *(f16x8*)(v16 + obase) = vh;
  }
  // split3 -> LDS (identical per-element arithmetic -> bit-identical buckets)
  {
    int rx = r & 7;
    f16x8 hv, mv, lv;
#pragma unroll
    for (int e = 0; e < 8; ++e) {
      _Float16 h0, m0, l0;
      split3(x[e], h0, m0, l0);
      hv[e] = h0; mv[e] = m0; lv[e] = l0;
    }
    int off = r * 64 + ((fq8 ^ rx) << 3);
    *(f16x8*)&ah[off] = hv;
    *(f16x8*)&am[off] = mv;
    *(f16x8*)&al[off] = lv;
  }
  __syncthreads();

  // ---- norm + qk16n + nq emission ----
  {
    float tot = 0.f;
#pragma unroll
    for (int g = 0; g < 8; ++g) tot += rsum[g * 32 + r];
    float nrm = fmaxf(sqrtf(tot), 1e-12f);
    float inv = 1.f / nrm;
    f16x8 qh;
#pragma unroll
    for (int e = 0; e < 8; ++e) qh[e] = (_Float16)(x[e] * inv);
    *(f16x8*)(qk16n + obase) = qh;
    if (fq8 == 0) nq[(size_t)bh * 4096 + tt * 32 + r] = nrm * LOG2E;
  }

  int w = tid >> 6, l = tid & 63;
  int col = l & 15, kg = l >> 4;

  float bv[2][4];
  int   bi[2][4];

#pragma unroll
  for (int nt = 0; nt < 4; ++nt) {
    int nrow = w * 64 + nt * 16 + col;
    const _Float16* bh_p = rth + nrow * 64 + kg * 8;
    const _Float16* bm_p = rtm + nrow * 64 + kg * 8;
    const _Float16* bl_p = rtl + nrow * 64 + kg * 8;
    f16x8 Bh0 = *(const f16x8*)(bh_p),      Bh1 = *(const f16x8*)(bh_p + 32);
    f16x8 Bm0 = *(const f16x8*)(bm_p),      Bm1 = *(const f16x8*)(bm_p + 32);
    f16x8 Bl0 = *(const f16x8*)(bl_p),      Bl1 = *(const f16x8*)(bl_p + 32);

    f32x4 C0[2], C1[2], C2[2];
#pragma unroll
    for (int mt = 0; mt < 2; ++mt) {
      C0[mt] = (f32x4){0.f, 0.f, 0.f, 0.f};
      C1[mt] = (f32x4){0.f, 0.f, 0.f, 0.f};
      C2[mt] = (f32x4){0.f, 0.f, 0.f, 0.f};
    }

    __builtin_amdgcn_s_setprio(1);
#pragma unroll
    for (int mt = 0; mt < 2; ++mt) {
      int ar = mt * 16 + col, arx = ar & 7;
#pragma unroll
      for (int kh = 0; kh < 2; ++kh) {
        int slot = kh * 4 + kg;
        f16x8 Ah = *(f16x8*)&ah[ar * 64 + ((slot ^ arx) << 3)];
        f16x8 Am = *(f16x8*)&am[ar * 64 + ((slot ^ arx) << 3)];
        f16x8 Al = *(f16x8*)&al[ar * 64 + ((slot ^ arx) << 3)];
        f16x8 Bh = kh ? Bh1 : Bh0;
        f16x8 Bm = kh ? Bm1 : Bm0;
        f16x8 Bl = kh ? Bl1 : Bl0;
        C2[mt] = __builtin_amdgcn_mfma_f32_16x16x32_f16(Ah, Bl, C2[mt], 0, 0, 0);
        C2[mt] = __builtin_amdgcn_mfma_f32_16x16x32_f16(Al, Bh, C2[mt], 0, 0, 0);
        C2[mt] = __builtin_amdgcn_mfma_f32_16x16x32_f16(Am, Bm, C2[mt], 0, 0, 0);
        C1[mt] = __builtin_amdgcn_mfma_f32_16x16x32_f16(Ah, Bm, C1[mt], 0, 0, 0);
        C1[mt] = __builtin_amdgcn_mfma_f32_16x16x32_f16(Am, Bh, C1[mt], 0, 0, 0);
        C0[mt] = __builtin_amdgcn_mfma_f32_16x16x32_f16(Ah, Bh, C0[mt], 0, 0, 0);
      }
    }
    __builtin_amdgcn_s_setprio(0);

    int ib = (nt & 1) * 16 + col;
#pragma unroll
    for (int mt = 0; mt < 2; ++mt) {
#pragma unroll
      for (int r2 = 0; r2 < 4; ++r2) {
        float V = C0[mt][r2] + C1[mt][r2] * S11 + C2[mt][r2] * S22;
        float av = fabsf(V);
        int fi = (V >= 0.f) ? ib : ib + 32;   // V==0 -> +side (lower idx)
        if ((nt & 1) == 0) {
          bv[mt][r2] = av; bi[mt][r2] = fi;
        } else {
          if (av > bv[mt][r2] || (av == bv[mt][r2] && fi < bi[mt][r2])) {
            bv[mt][r2] = av; bi[mt][r2] = fi;
          }
        }
      }
    }

    if (nt & 1) {
      int h = w * 2 + (nt >> 1);
#pragma unroll
      for (int mt = 0; mt < 2; ++mt) {
#pragma unroll
        for (int r2 = 0; r2 < 4; ++r2) {
          float v = bv[mt][r2]; int i_ = bi[mt][r2];
#pragma unroll
          for (int d = 1; d < 16; d <<= 1) {
            float ov = __shfl_xor(v, d);
            int   oi = __shfl_xor(i_, d);
            if (ov > v || (ov == v && oi < i_)) { v = ov; i_ = oi; }
          }
          if (col == 0) {
            int t = tt * 32 + mt * 16 + kg * 4 + r2;
            buckets[(bh * 8 + h) * 4096 + t] = (uint8_t)i_;
          }
        }
      }
    }
  }
}

// ============================================================
// K2: FUSED hist+scan+rank (r17-verified).
// ============================================================
__global__ __launch_bounds__(64) void k_sort(const uint8_t* __restrict__ buckets,
                                             int* __restrict__ sorted) {
  __shared__ uint8_t bkt[4096];
  __shared__ uint8_t lrk[4096];
  __shared__ int hist[64 * 65];
  __shared__ int sbase[64];
  int tid = threadIdx.x;
  int bh = blockIdx.x >> 3, h = blockIdx.x & 7;

  const int* src = (const int*)(buckets + (size_t)(bh * 8 + h) * 4096);
  for (int k = tid; k < 1024; k += 64) ((int*)bkt)[k] = src[k];
  for (int k = tid; k < 64 * 65; k += 64) hist[k] = 0;
  __syncthreads();

  {
    int c = tid;
    for (int k = 0; k < 64; ++k) {
      int t = c * 64 + k;
      int bin = bkt[t];
      int r = hist[c * 65 + bin];
      hist[c * 65 + bin] = r + 1;
      lrk[t] = (uint8_t)r;
    }
  }
  __syncthreads();

  int run = 0;
  {
    int bb = tid;
    for (int c2 = 0; c2 < 64; ++c2) {
      int val = hist[c2 * 65 + bb];
      hist[c2 * 65 + bb] = run;
      run += val;
    }
  }
  {
    int ex = run;
#pragma unroll
    for (int d = 1; d < 64; d <<= 1) {
      int o = __shfl_up(ex, d);
      if (tid >= d) ex += o;
    }
    ex -= run;                    // exclusive
    sbase[tid] = h * 4096 + ex;   // segment base + local base
  }
  __syncthreads();

  {
    int c = tid;
    int* dst = sorted + (size_t)bh * 32768;
    for (int k = 0; k < 64; ++k) {
      int t = c * 64 + k;
      int bin = bkt[t];
      int pos = sbase[bin] + hist[c * 65 + bin] + (int)lrk[t];
      dst[pos] = h * 4096 + t;
    }
  }
}

// ============================================================
// K3: chunked attention, fp16 MFMA — r15 structure, XCD-local
// grid, hash-innermost o/lse layout (unchanged).
// ============================================================
__global__ __launch_bounds__(256, 4) void k_attn(const _Float16* __restrict__ qk16n,
                                                 const _Float16* __restrict__ v16,
                                                 const float* __restrict__ nq,
                                                 const int* __restrict__ sorted,
                                                 _Float16* __restrict__ o_buf,
                                                 float* __restrict__ lse_buf) {
  __shared__ __attribute__((aligned(16))) _Float16 kf[128 * 64];
  __shared__ __attribute__((aligned(16))) _Float16 vt[64 * 128];
  __shared__ __attribute__((aligned(16))) float pinv_s[64];
  __shared__ __attribute__((aligned(16))) int tv[128];
  __shared__ __attribute__((aligned(16))) int items[64];

  int tid = threadIdx.x;
  int bh = blockIdx.x & 15;      // XCD-local decode
  int c  = blockIdx.x >> 4;

  if (tid < 128) {
    int r = tid;
    int pos = (r < 64) ? (c * 64 + r) : (((c + 511) & 511) * 64 + (r - 64));
    int item = sorted[(size_t)bh * 32768 + pos];
    tv[r] = item & 4095;
    if (r < 64) items[r] = item;
  }
  __syncthreads();

  int w = tid >> 6;
  int l = tid & 63;
  int col = l & 15;
  int kg = l >> 4;
  int rq = w * 16 + col;
  int rqx7 = rq & 7, rqx15 = rq & 15;
  int tq = tv[rq];
  float nqv = nq[(size_t)bh * 4096 + tq];

  {
    int r = tid >> 1, half = tid & 1;
    int t = tv[r];
    const f16x8* src = (const f16x8*)(qk16n + ((size_t)(bh * 4096 + t)) * 64 + half * 32);
    f16x8 d0 = src[0], d1 = src[1], d2 = src[2], d3 = src[3];
    int rx = r & 7, s0 = half * 4;
    *(f16x8*)&kf[r * 64 + (((s0 + 0) ^ rx) << 3)] = d0;
    *(f16x8*)&kf[r * 64 + (((s0 + 1) ^ rx) << 3)] = d1;
    *(f16x8*)&kf[r * 64 + (((s0 + 2) ^ rx) << 3)] = d2;
    *(f16x8*)&kf[r * 64 + (((s0 + 3) ^ rx) << 3)] = d3;
  }

  {
    int jp = tid & 63, db = tid >> 6, f0 = db * 16;
    int t0 = tv[2 * jp], t1 = tv[2 * jp + 1];
    const u32x4* s0p = (const u32x4*)(v16 + ((size_t)(bh * 4096 + t0)) * 64 + f0);
    const u32x4* s1p = (const u32x4*)(v16 + ((size_t)(bh * 4096 + t1)) * 64 + f0);
    u32x4 lo0 = s0p[0], hi0 = s0p[1];
    u32x4 lo1 = s1p[0], hi1 = s1p[1];
    int jbase = ((jp >> 2));
    int joff = (jp & 3) << 1;
#pragma unroll
    for (int i = 0; i < 16; ++i) {
      int d = f0 + i;
      unsigned a = (i < 8) ? lo0[(i >> 1) & 3] : hi0[(i >> 1) & 3];
      unsigned bsrc = (i < 8) ? lo1[(i >> 1) & 3] : hi1[(i >> 1) & 3];
      unsigned sel = (i & 1) ? 0x07060302u : 0x05040100u;
      unsigned pack = __builtin_amdgcn_perm(bsrc, a, sel);
      *(unsigned*)&vt[d * 128 + ((jbase ^ (d & 15)) << 3) + joff] = pack;
    }
  }
  __syncthreads();

  f16x8 qf[2];
#pragma unroll
  for (int ks = 0; ks < 2; ++ks)
    qf[ks] = *(f16x8*)&kf[rq * 64 + (((ks * 4 + kg) ^ rqx7) << 3)];

  f32x4 S[8];
#pragma unroll
  for (int mt = 0; mt < 8; ++mt) S[mt] = (f32x4){0.f, 0.f, 0.f, 0.f};

  __builtin_amdgcn_s_setprio(1);
#pragma unroll
  for (int mt = 0; mt < 8; ++mt) {
    int rj = mt * 16 + col;
    int rjx = rj & 7;
#pragma unroll
    for (int ks = 0; ks < 2; ++ks) {
      f16x8 a = *(f16x8*)&kf[rj * 64 + (((ks * 4 + kg) ^ rjx) << 3)];
      S[mt] = __builtin_amdgcn_mfma_f32_16x16x32_f16(a, qf[ks], S[mt], 0, 0, 0);
    }
  }
  __builtin_amdgcn_s_setprio(0);

  float vals[32];
  float mx = -1e30f;
#pragma unroll
  for (int mt = 0; mt < 8; ++mt) {
    int j0 = mt * 16 + kg * 4;
    int4 tk4 = *(int4*)&tv[j0];
    int tki[4] = {tk4.x, tk4.y, tk4.z, tk4.w};
#pragma unroll
    for (int r = 0; r < 4; ++r) {
      float d = S[mt][r] * nqv;
      if (tki[r] == tq) d = -50000.0f * LOG2E;
      vals[mt * 4 + r] = d;
      mx = fmaxf(mx, d);
    }
  }
  mx = fmaxf(mx, __shfl_xor(mx, 16));
  mx = fmaxf(mx, __shfl_xor(mx, 32));
  float ssum = 0.f;
#pragma unroll
  for (int i = 0; i < 32; ++i) {
    float e = __builtin_amdgcn_exp2f(vals[i] - mx);
    vals[i] = e;
    ssum += e;
  }
  ssum += __shfl_xor(ssum, 16);
  ssum += __shfl_xor(ssum, 32);
  if (kg == 0) {
    int item = items[rq];
    lse_buf[((size_t)bh * 4096 + (item & 4095)) * 8 + (item >> 12)] =
        (mx + __builtin_amdgcn_logf(ssum)) * LN2;
    pinv_s[rq] = 1.f / ssum;
  }

  __syncthreads();

  _Float16* Pb = kf;
#pragma unroll
  for (int mt = 0; mt < 8; ++mt) {
    int j0 = mt * 16 + kg * 4;
    int slot = j0 >> 3;
    int off = rq * 128 + ((slot ^ rqx15) << 3) + ((kg & 1) << 2);
    f16x4 pk;
#pragma unroll
    for (int r = 0; r < 4; ++r) pk[r] = (_Float16)vals[mt * 4 + r];
    *(f16x4*)&Pb[off] = pk;
  }
  asm volatile("s_waitcnt lgkmcnt(0)" ::: "memory");

  f32x4 O[4];
#pragma unroll
  for (int nt = 0; nt < 4; ++nt) O[nt] = (f32x4){0.f, 0.f, 0.f, 0.f};
  __builtin_amdgcn_s_setprio(1);
#pragma unroll
  for (int ks = 0; ks < 4; ++ks) {
    int slot = (ks << 2) + kg;
    f16x8 pa = *(f16x8*)&Pb[rq * 128 + ((slot ^ rqx15) << 3)];
#pragma unroll
    for (int nt = 0; nt < 4; ++nt) {
      int dD = nt * 16 + col;
      f16x8 vb = *(f16x8*)&vt[dD * 128 + ((slot ^ (dD & 15)) << 3)];
      O[nt] = __builtin_amdgcn_mfma_f32_16x16x32_f16(pa, vb, O[nt], 0, 0, 0);
    }
  }
  __builtin_amdgcn_s_setprio(0);

  {
    int i0 = w * 16 + kg * 4;
    int4 it4 = *(int4*)&items[i0];
    float4 pv4 = *(float4*)&pinv_s[i0];
    int iti[4] = {it4.x, it4.y, it4.z, it4.w};
    float pvi[4] = {pv4.x, pv4.y, pv4.z, pv4.w};
#pragma unroll
    for (int r = 0; r < 4; ++r) {
      int item = iti[r];
      _Float16* orow = o_buf +
          (((size_t)bh * 4096 + (item & 4095)) * 8 + (item >> 12)) * 64;
#pragma unroll
      for (int nt = 0; nt < 4; ++nt) orow[nt * 16 + col] = (_Float16)(O[nt][r] * pvi[r]);
    }
  }
}

// ============================================================
// K4: combine 8 hash rounds — hash-innermost layout (r18).
// ============================================================
__global__ __launch_bounds__(256) void k_combine(const _Float16* __restrict__ o_buf,
                                                 const float* __restrict__ lse_buf,
                                                 float* __restrict__ out) {
  int gid = blockIdx.x * 256 + threadIdx.x;  // < 16*4096*16
  int d4 = gid & 15;
  int t  = (gid >> 4) & 4095;
  int bh = gid >> 16;

  const float* lrow = lse_buf + ((size_t)bh * 4096 + t) * 8;
  float lx[8];
#pragma unroll
  for (int h = 0; h < 8; ++h) lx[h] = lrow[h];
  float m = lx[0];
#pragma unroll
  for (int h = 1; h < 8; ++h) m = fmaxf(m, lx[h]);
  float wv[8]; float s = 0.f;
#pragma unroll
  for (int h = 0; h < 8; ++h) { wv[h] = __expf(lx[h] - m); s += wv[h]; }
  float inv = 1.f / s;

  const _Float16* obase = o_buf + ((size_t)bh * 4096 + t) * 8 * 64 + d4 * 4;
  float ax = 0.f, ay = 0.f, az = 0.f, aw = 0.f;
#pragma unroll
  for (int h = 0; h < 8; ++h) {
    f16x4 ov = *(const f16x4*)(obase + h * 64);
    ax = fmaf(wv[h], (float)ov[0], ax);
    ay = fmaf(wv[h], (float)ov[1], ay);
    az = fmaf(wv[h], (float)ov[2], az);
    aw = fmaf(wv[h], (float)ov[3], aw);
  }
  *(float4*)(out + ((size_t)(bh * 4096 + t)) * 64 + d4 * 4) =
      make_float4(ax * inv, ay * inv, az * inv, aw * inv);
}

// ============================================================
extern "C" void kernel_launch(void* const* d_in, const int* in_sizes, int n_in,
                              void* d_out, int out_size, void* d_ws, size_t ws_size,
                              hipStream_t stream) {
  const float* qk  = (const float*)d_in[0];
  // d_in[1] ("k") is unused by the reference
  const float* vin = (const float*)d_in[2];
  const float* rot = (const float*)d_in[3];

  uint8_t* ws = (uint8_t*)d_ws;
  uint8_t*  buckets = ws + WS_BUCKETS;
  int*      sorted  = (int*)(ws + WS_SORTED);
  float*    lse_buf = (float*)(ws + WS_LSE);
  _Float16* o_buf   = (_Float16*)(ws + WS_O);
  _Float16* qk16n   = (_Float16*)(ws + WS_QK16);
  _Float16* v16     = (_Float16*)(ws + WS_V16);
  float*    nqbuf   = (float*)(ws + WS_NQ);
  _Float16* rth     = (_Float16*)(ws + WS_RTH);
  _Float16* rtm     = (_Float16*)(ws + WS_RTM);
  _Float16* rtl     = (_Float16*)(ws + WS_RTL);
  float*    out     = (float*)d_out;

  k_rotsplit<<<64, 256, 0, stream>>>(rot, rth, rtm, rtl);
  k_hash2<<<BHN * 128, 256, 0, stream>>>(qk, vin, rth, rtm, rtl, buckets,
                                         qk16n, v16, nqbuf);
  k_sort<<<BHN * NHASH, 64, 0, stream>>>(buckets, sorted);
  k_attn<<<BHN * NCHUNK, 256, 0, stream>>>(qk16n, v16, nqbuf, sorted, o_buf, lse_buf);
  k_combine<<<4096, 256, 0, stream>>>(o_buf, lse_buf, out);
}